// Round 16
// baseline (93.045 us; speedup 1.0000x reference)
//
#include <hip/hip_runtime.h>
#include <hip/hip_bf16.h>

#define NB 32768      // batch rows per node
#define CD 128        // input channels
#define NNODES 6
#define OUTW 1536     // 6*256 output cols
#define KW 256        // concat K per node GEMM
#define GPB 8         // row-groups per persistent block
#define NBLK (NB / 16 / GPB)   // 256 blocks = 1 per CU

typedef __attribute__((ext_vector_type(8))) short short8;
typedef __attribute__((ext_vector_type(4))) short s16x4;   // 'short4' is a HIP builtin
typedef __attribute__((ext_vector_type(4))) float f32x4;

// hardware f32->bf16 (RNE)
static __device__ __forceinline__ short f2bf(float f) {
    union { __bf16 b; short s; } u;
    u.b = (__bf16)f;
    return u.s;
}

static __device__ __forceinline__ short8 pack8(f32x4 a, f32x4 b) {
    short8 p;
    #pragma unroll
    for (int j = 0; j < 4; ++j) { p[j] = f2bf(a[j]); p[4 + j] = f2bf(b[j]); }
    return p;
}

static __device__ __forceinline__ s16x4 pack4(f32x4 a) {
    s16x4 p;
    #pragma unroll
    for (int j = 0; j < 4; ++j) p[j] = f2bf(a[j]);
    return p;
}

// ---- prologue: Wcat[o][k] bf16 in d_ws; k<128 -> Wl[o][k], else Wr[o][k-128]
__global__ void prep_w(const float* __restrict__ Wl, const float* __restrict__ Wr,
                       short* __restrict__ Wb) {
    const int i = (blockIdx.x * 256 + threadIdx.x) * 8;
    const int o = i >> 8;
    const int k = i & 255;
    const float* src = (k < 128) ? (Wl + o * CD + k) : (Wr + o * CD + (k - 128));
    *(short8*)(Wb + i) = pack8(*(const f32x4*)src, *(const f32x4*)(src + 4));
}

// LDS short-index, XOR swizzle (byte ^= (r&7)<<4): panel p(0..9), row r(0..15),
// k(0..127). Bijective for 8B/16B accesses; reads 2-way max. Verified R5-R15.
// Panels: 0:g0 1:g1 2:g25 3:g34 4..9:x0..x5
#define LIDX(p, r, k) ((((p) << 11) + ((r) << 7) + (k)) ^ (((r) & 7) << 3))

// R16 = R15 with the store-drain removed (T4 counted-vmcnt pattern):
//  - mid-iter wait is vmcnt(8): per-wave VMEM order is [4 prev-stores][6 DMA
//    loads][8 stores], so allowing the 8 newest to remain outstanding
//    guarantees the DMA loads retired WITHOUT flushing the store queue.
//  - barrier is raw s_barrier preceded by lgkmcnt(0) (publishes convert's
//    ds_writes cross-wave); never vmcnt(0). Stores drain continuously in
//    the background at HBM rate; HW FIFO flow-control is the only pacing.
//  - W fragments stay hoisted in regs: the vmcnt FIFO holds ONLY the 6
//    loads + 12 stores per iter (clean counted-wait semantics).
__global__ __launch_bounds__(512, 1)
void sage_v14(const float* __restrict__ x, const short* __restrict__ Wb,
              const float* __restrict__ bias, float* __restrict__ out) {
    __shared__ __align__(16) float raw[NNODES * 16 * 128];   // 48 KB, single
    __shared__ __align__(16) short A[2][10 * 16 * 128];      // 2 x 40 KB

    const int t = threadIdx.x;
    const int r = t >> 5;          // staging/convert row 0..15
    const int c = t & 31;          // 4-float chunk 0..31
    const int lane = t & 63;
    const int wv = t >> 6;         // wave 0..7
    const int lo = lane & 15;
    const int hi = lane >> 4;
    const int obase = wv * 32;     // 32-col strip per wave (R10-validated)
    const size_t rg0 = (size_t)blockIdx.x * GPB;

    f32x4 bias4[2];
    #pragma unroll
    for (int i = 0; i < 2; ++i)
        bias4[i] = *(const f32x4*)&bias[obase + i * 16 + hi * 4];

    short8 wfa[4][2], wfx[4][2];   // [m][i], 64 VGPRs, iter/pair-invariant
    #pragma unroll
    for (int m = 0; m < 4; ++m)
        #pragma unroll
        for (int i = 0; i < 2; ++i) {
            const int kk = m * 32 + hi * 8;
            const int o = obase + i * 16 + lo;
            wfa[m][i] = *(const short8*)&Wb[o * KW + kk];          // Wl half
            wfx[m][i] = *(const short8*)&Wb[o * KW + 128 + kk];    // Wr half
        }

    auto stage = [&](size_t rg) {
        const float* gp = x + (rg * 16 + r) * CD + c * 4;
        #pragma unroll
        for (int s = 0; s < NNODES; ++s) {
            __builtin_amdgcn_global_load_lds(
                (const __attribute__((address_space(1))) void*)(gp + (size_t)s * (NB * CD)),
                (__attribute__((address_space(3))) void*)&raw[s * 2048 + wv * 256],
                16, 0, 0);
        }
    };

    auto convert = [&](short* __restrict__ Ad) {
        const int base = r * 128 + c * 4;
        f32x4 v0 = *(const f32x4*)&raw[0 * 2048 + base];
        f32x4 v1 = *(const f32x4*)&raw[1 * 2048 + base];
        f32x4 v2 = *(const f32x4*)&raw[2 * 2048 + base];
        f32x4 v3 = *(const f32x4*)&raw[3 * 2048 + base];
        f32x4 v4 = *(const f32x4*)&raw[4 * 2048 + base];
        f32x4 v5 = *(const f32x4*)&raw[5 * 2048 + base];
        f32x4 S01 = v0 + v1, S25 = v2 + v5, S34 = v3 + v4;
        f32x4 T = S01 + S25 + S34;
        const int k = c * 4;
        *(s16x4*)&Ad[LIDX(0, r, k)] = pack4((T - v0) * 0.2f);      // g0
        *(s16x4*)&Ad[LIDX(1, r, k)] = pack4((T - v1) * 0.2f);      // g1
        *(s16x4*)&Ad[LIDX(2, r, k)] = pack4((S01 + S34) * 0.25f);  // g25
        *(s16x4*)&Ad[LIDX(3, r, k)] = pack4((S01 + S25) * 0.25f);  // g34
        *(s16x4*)&Ad[LIDX(4, r, k)] = pack4(v0);
        *(s16x4*)&Ad[LIDX(5, r, k)] = pack4(v1);
        *(s16x4*)&Ad[LIDX(6, r, k)] = pack4(v2);
        *(s16x4*)&Ad[LIDX(7, r, k)] = pack4(v3);
        *(s16x4*)&Ad[LIDX(8, r, k)] = pack4(v4);
        *(s16x4*)&Ad[LIDX(9, r, k)] = pack4(v5);
    };

    auto pairMFMA = [&](const short* __restrict__ Ab, int pa0, int pa1,
                        int px0, int px1, f32x4 acc[2][2]) {
        #pragma unroll
        for (int n = 0; n < 2; ++n)
            #pragma unroll
            for (int i = 0; i < 2; ++i) acc[n][i] = (f32x4){0.f, 0.f, 0.f, 0.f};
        #pragma unroll
        for (int m = 0; m < 4; ++m) {
            const int kk = m * 32 + hi * 8;
            short8 fa0 = *(const short8*)&Ab[LIDX(pa0, lo, kk)];
            short8 fa1 = *(const short8*)&Ab[LIDX(pa1, lo, kk)];
            short8 fx0 = *(const short8*)&Ab[LIDX(px0, lo, kk)];
            short8 fx1 = *(const short8*)&Ab[LIDX(px1, lo, kk)];
            #pragma unroll
            for (int i = 0; i < 2; ++i) {
                acc[0][i] = __builtin_amdgcn_mfma_f32_16x16x32_bf16(wfa[m][i], fa0, acc[0][i], 0, 0, 0);
                acc[1][i] = __builtin_amdgcn_mfma_f32_16x16x32_bf16(wfa[m][i], fa1, acc[1][i], 0, 0, 0);
                acc[0][i] = __builtin_amdgcn_mfma_f32_16x16x32_bf16(wfx[m][i], fx0, acc[0][i], 0, 0, 0);
                acc[1][i] = __builtin_amdgcn_mfma_f32_16x16x32_bf16(wfx[m][i], fx1, acc[1][i], 0, 0, 0);
            }
        }
    };

    auto storePair = [&](int n0, int n1, f32x4 acc[2][2], size_t orow) {
        #pragma unroll
        for (int w = 0; w < 2; ++w) {
            const int node = w ? n1 : n0;
            #pragma unroll
            for (int i = 0; i < 2; ++i) {
                const int ocol = obase + i * 16 + hi * 4;
                f32x4 v = acc[w][i] + bias4[i];
                f32x4 g;
                #pragma unroll
                for (int j = 0; j < 4; ++j) {
                    const float s = v[j] * (0.7978845608f + 0.0356774081f * v[j] * v[j]);
                    const float rr = __builtin_amdgcn_exp2f(-2.885390082f * s);
                    g[j] = v[j] * __builtin_amdgcn_rcpf(1.0f + rr);
                }
                *(f32x4*)&out[orow * OUTW + node * 256 + ocol] = g;
            }
        }
    };

    // ---- prologue: group 0 into A[0] (only DMA loads outstanding -> vmcnt(0) ok)
    stage(rg0);
    asm volatile("s_waitcnt vmcnt(0)" ::: "memory");
    __builtin_amdgcn_sched_barrier(0);
    convert(&A[0][0]);
    asm volatile("s_waitcnt lgkmcnt(0)" ::: "memory");
    __builtin_amdgcn_sched_barrier(0);
    __builtin_amdgcn_s_barrier();      // publish A[0]

    f32x4 accH[2][2];
    size_t prevRow = 0;

    #pragma unroll 1
    for (int it = 0; it < GPB; ++it) {
        const short* Ab = &A[it & 1][0];
        const size_t orow = (rg0 + it) * 16 + lo;

        if (it) storePair(3, 4, accH, prevRow);       // 4 stores (oldest)
        if (it + 1 < GPB) stage(rg0 + it + 1);        // 6 DMA loads

        f32x4 acc[2][2];
        pairMFMA(Ab, 0, 1, 4, 5, acc);   // nodes 0,1 (g0,g1)
        storePair(0, 1, acc, orow);                   // 4 stores
        pairMFMA(Ab, 2, 2, 6, 9, acc);   // nodes 2,5 (shared g25)
        storePair(2, 5, acc, orow);                   // 4 stores
        pairMFMA(Ab, 3, 3, 7, 8, accH);  // nodes 3,4 (shared g34) -> held
        prevRow = orow;

        if (it + 1 < GPB) {
            // counted wait: 8 newest stores may stay outstanding; guarantees
            // the 6 DMA loads (older) retired. NEVER drains the store queue.
            asm volatile("s_waitcnt vmcnt(8)" ::: "memory");
            __builtin_amdgcn_sched_barrier(0);
            convert(&A[(it + 1) & 1][0]);
        }
        asm volatile("s_waitcnt lgkmcnt(0)" ::: "memory");
        __builtin_amdgcn_sched_barrier(0);
        __builtin_amdgcn_s_barrier();                 // publish A[(it+1)&1]
    }
    storePair(3, 4, accH, prevRow);      // final held pair (drains at endpgm)
}

extern "C" void kernel_launch(void* const* d_in, const int* in_sizes, int n_in,
                              void* d_out, int out_size, void* d_ws, size_t ws_size,
                              hipStream_t stream) {
    const float* x  = (const float*)d_in[0];
    const float* Wl = (const float*)d_in[1];
    const float* Wr = (const float*)d_in[2];
    const float* b  = (const float*)d_in[3];
    float* out = (float*)d_out;
    short* Wb = (short*)d_ws;   // 256*256 bf16 = 128 KB

    prep_w<<<dim3(32), dim3(256), 0, stream>>>(Wl, Wr, Wb);
    sage_v14<<<dim3(NBLK), dim3(512), 0, stream>>>(x, Wb, b, out);
}

// Round 17
// 92.060 us; speedup vs baseline: 1.0107x; 1.0107x over previous
//
#include <hip/hip_runtime.h>
#include <hip/hip_bf16.h>

#define NB 32768      // batch rows per node
#define CD 128        // input channels
#define NNODES 6
#define OUTW 1536     // 6*256 output cols
#define KW 256        // concat K per node GEMM
#define GPB 8         // row-groups per persistent block
#define NBLK (NB / 16 / GPB)   // 256 blocks = 1 per CU

typedef __attribute__((ext_vector_type(8))) short short8;
typedef __attribute__((ext_vector_type(4))) short s16x4;   // 'short4' is a HIP builtin
typedef __attribute__((ext_vector_type(4))) float f32x4;

// hardware f32->bf16 (RNE)
static __device__ __forceinline__ short f2bf(float f) {
    union { __bf16 b; short s; } u;
    u.b = (__bf16)f;
    return u.s;
}

static __device__ __forceinline__ short8 pack8(f32x4 a, f32x4 b) {
    short8 p;
    #pragma unroll
    for (int j = 0; j < 4; ++j) { p[j] = f2bf(a[j]); p[4 + j] = f2bf(b[j]); }
    return p;
}

static __device__ __forceinline__ s16x4 pack4(f32x4 a) {
    s16x4 p;
    #pragma unroll
    for (int j = 0; j < 4; ++j) p[j] = f2bf(a[j]);
    return p;
}

// ---- prologue: Wcat[o][k] bf16 in d_ws; k<128 -> Wl[o][k], else Wr[o][k-128]
__global__ void prep_w(const float* __restrict__ Wl, const float* __restrict__ Wr,
                       short* __restrict__ Wb) {
    const int i = (blockIdx.x * 256 + threadIdx.x) * 8;
    const int o = i >> 8;
    const int k = i & 255;
    const float* src = (k < 128) ? (Wl + o * CD + k) : (Wr + o * CD + (k - 128));
    *(short8*)(Wb + i) = pack8(*(const f32x4*)src, *(const f32x4*)(src + 4));
}

// LDS short-index, XOR swizzle (byte ^= (r&7)<<4): panel p(0..9), row r(0..15),
// k(0..127). Bijective for 8B/16B accesses; reads 2-way max. Verified R5-R16.
// Panels: 0:g0 1:g1 2:g25 3:g34 4..9:x0..x5
#define LIDX(p, r, k) ((((p) << 11) + ((r) << 7) + (k)) ^ (((r) & 7) << 3))

// R17 = R13 VERBATIM except the store schedule: pair2 AND pair3 accumulators
// are held across the barrier and their 8 stores issue at the TOP of the
// next iteration. Store drain windows (before the nearest vmcnt(0)-bearing
// __syncthreads): pair1 >= 2/3 MFMA phase, pairs 2+3 = full MFMA phase.
// NO stores issue between barrier1 and barrier2 (R13 had pair3's 4 stores
// draining in the short convert window -- the last exposed drain).
// LDS 136KB -> 1 block/CU -> 2 waves/SIMD -> 256-VGPR budget; held accs
// (+32 regs) are free (launch_bounds(512,1); R15 proved no spill).
__global__ __launch_bounds__(512, 1)
void sage_v15(const float* __restrict__ x, const short* __restrict__ Wb,
              const float* __restrict__ bias, float* __restrict__ out) {
    __shared__ __align__(16) float raw[2][NNODES * 16 * 128];   // 2 x 48 KB, linear
    __shared__ __align__(16) short A[10 * 16 * 128];            // 40 KB panels

    const int t = threadIdx.x;
    const int r = t >> 5;          // staging/convert row 0..15
    const int c = t & 31;          // 4-float chunk 0..31
    const int lane = t & 63;
    const int wv = t >> 6;         // wave 0..7
    const int lo = lane & 15;
    const int hi = lane >> 4;
    const int obase = wv * 32;     // 32-col strip per wave (R10-validated)
    const size_t rg0 = (size_t)blockIdx.x * GPB;

    f32x4 bias4[2];
    #pragma unroll
    for (int i = 0; i < 2; ++i)
        bias4[i] = *(const f32x4*)&bias[obase + i * 16 + hi * 4];

    auto stage = [&](int buf, size_t rg) {
        const float* gp = x + (rg * 16 + r) * CD + c * 4;
        #pragma unroll
        for (int s = 0; s < NNODES; ++s) {
            __builtin_amdgcn_global_load_lds(
                (const __attribute__((address_space(1))) void*)(gp + (size_t)s * (NB * CD)),
                (__attribute__((address_space(3))) void*)&raw[buf][s * 2048 + wv * 256],
                16, 0, 0);
        }
    };

    auto convert = [&](int buf) {
        const float* rb = &raw[buf][0];
        const int base = r * 128 + c * 4;
        f32x4 v0 = *(const f32x4*)&rb[0 * 2048 + base];
        f32x4 v1 = *(const f32x4*)&rb[1 * 2048 + base];
        f32x4 v2 = *(const f32x4*)&rb[2 * 2048 + base];
        f32x4 v3 = *(const f32x4*)&rb[3 * 2048 + base];
        f32x4 v4 = *(const f32x4*)&rb[4 * 2048 + base];
        f32x4 v5 = *(const f32x4*)&rb[5 * 2048 + base];
        f32x4 S01 = v0 + v1, S25 = v2 + v5, S34 = v3 + v4;
        f32x4 T = S01 + S25 + S34;
        const int k = c * 4;
        *(s16x4*)&A[LIDX(0, r, k)] = pack4((T - v0) * 0.2f);      // g0
        *(s16x4*)&A[LIDX(1, r, k)] = pack4((T - v1) * 0.2f);      // g1
        *(s16x4*)&A[LIDX(2, r, k)] = pack4((S01 + S34) * 0.25f);  // g25
        *(s16x4*)&A[LIDX(3, r, k)] = pack4((S01 + S25) * 0.25f);  // g34
        *(s16x4*)&A[LIDX(4, r, k)] = pack4(v0);
        *(s16x4*)&A[LIDX(5, r, k)] = pack4(v1);
        *(s16x4*)&A[LIDX(6, r, k)] = pack4(v2);
        *(s16x4*)&A[LIDX(7, r, k)] = pack4(v3);
        *(s16x4*)&A[LIDX(8, r, k)] = pack4(v4);
        *(s16x4*)&A[LIDX(9, r, k)] = pack4(v5);
    };

    auto pairMFMA = [&](int pa0, int pa1, int px0, int px1, f32x4 acc[2][2]) {
        #pragma unroll
        for (int n = 0; n < 2; ++n)
            #pragma unroll
            for (int i = 0; i < 2; ++i) acc[n][i] = (f32x4){0.f, 0.f, 0.f, 0.f};
        #pragma unroll
        for (int m = 0; m < 4; ++m) {
            const int kk = m * 32 + hi * 8;
            short8 fa0 = *(const short8*)&A[LIDX(pa0, lo, kk)];
            short8 fa1 = *(const short8*)&A[LIDX(pa1, lo, kk)];
            short8 fx0 = *(const short8*)&A[LIDX(px0, lo, kk)];
            short8 fx1 = *(const short8*)&A[LIDX(px1, lo, kk)];
            #pragma unroll
            for (int i = 0; i < 2; ++i) {
                const int o = obase + i * 16 + lo;
                short8 wa = *(const short8*)&Wb[o * KW + kk];          // Wl half
                short8 wx = *(const short8*)&Wb[o * KW + 128 + kk];    // Wr half
                acc[0][i] = __builtin_amdgcn_mfma_f32_16x16x32_bf16(wa, fa0, acc[0][i], 0, 0, 0);
                acc[1][i] = __builtin_amdgcn_mfma_f32_16x16x32_bf16(wa, fa1, acc[1][i], 0, 0, 0);
                acc[0][i] = __builtin_amdgcn_mfma_f32_16x16x32_bf16(wx, fx0, acc[0][i], 0, 0, 0);
                acc[1][i] = __builtin_amdgcn_mfma_f32_16x16x32_bf16(wx, fx1, acc[1][i], 0, 0, 0);
            }
        }
    };

    auto storePair = [&](int n0, int n1, f32x4 acc[2][2], size_t orow) {
        #pragma unroll
        for (int w = 0; w < 2; ++w) {
            const int node = w ? n1 : n0;
            #pragma unroll
            for (int i = 0; i < 2; ++i) {
                const int ocol = obase + i * 16 + hi * 4;
                f32x4 v = acc[w][i] + bias4[i];
                f32x4 g;
                #pragma unroll
                for (int j = 0; j < 4; ++j) {
                    const float s = v[j] * (0.7978845608f + 0.0356774081f * v[j] * v[j]);
                    const float rr = __builtin_amdgcn_exp2f(-2.885390082f * s);
                    g[j] = v[j] * __builtin_amdgcn_rcpf(1.0f + rr);
                }
                *(f32x4*)&out[orow * OUTW + node * 256 + ocol] = g;
            }
        }
    };

    // ---- pipeline prologue: group 0 (R13-verbatim)
    stage(0, rg0);
    __syncthreads();               // drains DMA
    convert(0);
    __syncthreads();               // publish A for iter 0

    f32x4 accH2[2][2], accH3[2][2];   // pairs (2,5) and (3,4) held across barrier
    size_t prevRow = 0;

    #pragma unroll 1
    for (int it = 0; it < GPB; ++it) {
        const bool havenext = (it + 1 < GPB);
        const size_t orow = (rg0 + it) * 16 + lo;

        if (havenext) stage((it + 1) & 1, rg0 + it + 1);   // DMA heads the queue
        if (it) {                                          // prev group's held stores:
            storePair(2, 5, accH2, prevRow);               // full MFMA phase to drain
            storePair(3, 4, accH3, prevRow);
        }

        f32x4 acc[2][2];
        pairMFMA(0, 1, 4, 5, acc);            // nodes 0,1 (g0,g1)
        storePair(0, 1, acc, orow);           // >= 2/3 phase to drain
        pairMFMA(2, 2, 6, 9, accH2);          // nodes 2,5 (shared g25) -> held
        pairMFMA(3, 3, 7, 8, accH3);          // nodes 3,4 (shared g34) -> held
        prevRow = orow;

        __syncthreads();                      // barrier1: A reads done, DMA drained
        if (havenext) convert((it + 1) & 1);  // NO stores in this window
        __syncthreads();                      // barrier2: publish A
    }
    storePair(2, 5, accH2, prevRow);          // final held pairs
    storePair(3, 4, accH3, prevRow);
}

extern "C" void kernel_launch(void* const* d_in, const int* in_sizes, int n_in,
                              void* d_out, int out_size, void* d_ws, size_t ws_size,
                              hipStream_t stream) {
    const float* x  = (const float*)d_in[0];
    const float* Wl = (const float*)d_in[1];
    const float* Wr = (const float*)d_in[2];
    const float* b  = (const float*)d_in[3];
    float* out = (float*)d_out;
    short* Wb = (short*)d_ws;   // 256*256 bf16 = 128 KB

    prep_w<<<dim3(32), dim3(256), 0, stream>>>(Wl, Wr, Wb);
    sage_v15<<<dim3(NBLK), dim3(512), 0, stream>>>(x, Wb, b, out);
}

// Round 18
// 88.829 us; speedup vs baseline: 1.0475x; 1.0364x over previous
//
#include <hip/hip_runtime.h>
#include <hip/hip_bf16.h>

#define NB 32768      // batch rows per node
#define CD 128        // input channels (= K of every GEMM term now)
#define NNODES 6
#define OUTW 1536     // 6*256 output cols
#define GPB 8         // row-groups per persistent block
#define NBLK (NB / 16 / GPB)   // 256 blocks = 1 per CU

// d_ws weight matrices, each [256 out][128 k] bf16 (32768 shorts):
#define PW_P  0        // Wl            (U = T·Wl)
#define PW_M0 32768    // Wr - Wl/5     (nodes 0,1)
#define PW_M2 65536    // Wr - Wl/4     (nodes 2..5 own term)
#define PW_N  98304    // -Wl/4         (partner term)

typedef __attribute__((ext_vector_type(8))) short short8;
typedef __attribute__((ext_vector_type(4))) short s16x4;   // 'short4' is a HIP builtin
typedef __attribute__((ext_vector_type(4))) float f32x4;

// hardware f32->bf16 (RNE)
static __device__ __forceinline__ short f2bf(float f) {
    union { __bf16 b; short s; } u;
    u.b = (__bf16)f;
    return u.s;
}

static __device__ __forceinline__ short8 pack8(f32x4 a, f32x4 b) {
    short8 p;
    #pragma unroll
    for (int j = 0; j < 4; ++j) { p[j] = f2bf(a[j]); p[4 + j] = f2bf(b[j]); }
    return p;
}

static __device__ __forceinline__ s16x4 pack4(f32x4 a) {
    s16x4 p;
    #pragma unroll
    for (int j = 0; j < 4; ++j) p[j] = f2bf(a[j]);
    return p;
}

// ---- prologue: 4 combined weight matrices (aggregation pushed past the GEMM)
__global__ void prep_w(const float* __restrict__ Wl, const float* __restrict__ Wr,
                       short* __restrict__ Wb) {
    const int i = (blockIdx.x * 256 + threadIdx.x) * 8;   // o*128 + k
    const int o = i >> 7;
    const int k = i & 127;
    f32x4 l0 = *(const f32x4*)(Wl + o * CD + k);
    f32x4 l1 = *(const f32x4*)(Wl + o * CD + k + 4);
    f32x4 r0 = *(const f32x4*)(Wr + o * CD + k);
    f32x4 r1 = *(const f32x4*)(Wr + o * CD + k + 4);
    *(short8*)(Wb + PW_P  + i) = pack8(l0, l1);
    *(short8*)(Wb + PW_M0 + i) = pack8(r0 - 0.2f  * l0, r1 - 0.2f  * l1);
    *(short8*)(Wb + PW_M2 + i) = pack8(r0 - 0.25f * l0, r1 - 0.25f * l1);
    *(short8*)(Wb + PW_N  + i) = pack8(-0.25f * l0, -0.25f * l1);
}

// LDS short-index, XOR swizzle (byte ^= (r&7)<<4); bijective for 8B/16B
// accesses, reads 2-way max. Verified R5-R17. Panels: 0..5 = x0..x5, 6 = T.
#define LIDX(p, r, k) ((((p) << 11) + ((r) << 7) + (k)) ^ (((r) & 7) << 3))

// R18 = R13's exact pipeline/schedule with the post-GEMM-aggregation math:
// per iter: U-pass (8 MFMA) -> pair(0,1) 16 MFMA+store -> pair(2,5) 32
// MFMA+store -> pair(3,4) 32 MFMA held across barrier (R13's winning trick;
// U folded into acc immediately so held store needs no extra state).
// 88 MFMA/iter (was 96), 28 panel reads (was 48), 7 panels (was 10).
__global__ __launch_bounds__(512, 1)
void sage_v16(const float* __restrict__ x, const short* __restrict__ Wb,
              const float* __restrict__ bias, float* __restrict__ out) {
    __shared__ __align__(16) float raw[2][NNODES * 16 * 128];   // 2 x 48 KB
    __shared__ __align__(16) short A[7 * 16 * 128];             // 28 KB panels

    const int t = threadIdx.x;
    const int r = t >> 5;          // staging/convert row 0..15
    const int c = t & 31;          // 4-float chunk 0..31
    const int lane = t & 63;
    const int wv = t >> 6;         // wave 0..7
    const int lo = lane & 15;
    const int hi = lane >> 4;
    const int obase = wv * 32;     // 32-col strip per wave (R10-validated)
    const size_t rg0 = (size_t)blockIdx.x * GPB;

    f32x4 bias4[2];
    #pragma unroll
    for (int i = 0; i < 2; ++i)
        bias4[i] = *(const f32x4*)&bias[obase + i * 16 + hi * 4];

    auto stage = [&](int buf, size_t rg) {
        const float* gp = x + (rg * 16 + r) * CD + c * 4;
        #pragma unroll
        for (int s = 0; s < NNODES; ++s) {
            __builtin_amdgcn_global_load_lds(
                (const __attribute__((address_space(1))) void*)(gp + (size_t)s * (NB * CD)),
                (__attribute__((address_space(3))) void*)&raw[buf][s * 2048 + wv * 256],
                16, 0, 0);
        }
    };

    auto convert = [&](int buf) {
        const float* rb = &raw[buf][0];
        const int base = r * 128 + c * 4;
        f32x4 v0 = *(const f32x4*)&rb[0 * 2048 + base];
        f32x4 v1 = *(const f32x4*)&rb[1 * 2048 + base];
        f32x4 v2 = *(const f32x4*)&rb[2 * 2048 + base];
        f32x4 v3 = *(const f32x4*)&rb[3 * 2048 + base];
        f32x4 v4 = *(const f32x4*)&rb[4 * 2048 + base];
        f32x4 v5 = *(const f32x4*)&rb[5 * 2048 + base];
        f32x4 T = ((v0 + v1) + (v2 + v3)) + (v4 + v5);
        const int k = c * 4;
        *(s16x4*)&A[LIDX(0, r, k)] = pack4(v0);
        *(s16x4*)&A[LIDX(1, r, k)] = pack4(v1);
        *(s16x4*)&A[LIDX(2, r, k)] = pack4(v2);
        *(s16x4*)&A[LIDX(3, r, k)] = pack4(v3);
        *(s16x4*)&A[LIDX(4, r, k)] = pack4(v4);
        *(s16x4*)&A[LIDX(5, r, k)] = pack4(v5);
        *(s16x4*)&A[LIDX(6, r, k)] = pack4(T);
    };

    // GELU + store of a U-folded, bias-pending acc pair
    auto storePair = [&](int n0, int n1, f32x4 acc[2][2], size_t orow) {
        #pragma unroll
        for (int w = 0; w < 2; ++w) {
            const int node = w ? n1 : n0;
            #pragma unroll
            for (int i = 0; i < 2; ++i) {
                const int ocol = obase + i * 16 + hi * 4;
                f32x4 v = acc[w][i] + bias4[i];
                f32x4 g;
                #pragma unroll
                for (int j = 0; j < 4; ++j) {
                    const float s = v[j] * (0.7978845608f + 0.0356774081f * v[j] * v[j]);
                    const float rr = __builtin_amdgcn_exp2f(-2.885390082f * s);
                    g[j] = v[j] * __builtin_amdgcn_rcpf(1.0f + rr);
                }
                *(f32x4*)&out[orow * OUTW + node * 256 + ocol] = g;
            }
        }
    };

    // ---- pipeline prologue: group 0 (R13-verbatim)
    stage(0, rg0);
    __syncthreads();               // drains DMA
    convert(0);
    __syncthreads();               // publish A for iter 0

    f32x4 accH[2][2];              // pair (3,4), U already folded
    size_t prevRow = 0;

    #pragma unroll 1
    for (int it = 0; it < GPB; ++it) {
        const bool havenext = (it + 1 < GPB);
        const size_t orow = (rg0 + it) * 16 + lo;

        if (havenext) stage((it + 1) & 1, rg0 + it + 1);   // DMA heads the queue
        if (it) storePair(3, 4, accH, prevRow);            // full phase to drain

        // ---- U-pass: accU[i] = sum_m P-frag x T-frag
        f32x4 accU[2] = {(f32x4){0.f,0.f,0.f,0.f}, (f32x4){0.f,0.f,0.f,0.f}};
        #pragma unroll
        for (int m = 0; m < 4; ++m) {
            const int kk = m * 32 + hi * 8;
            short8 ft = *(const short8*)&A[LIDX(6, lo, kk)];
            #pragma unroll
            for (int i = 0; i < 2; ++i) {
                const int o = obase + i * 16 + lo;
                short8 wp = *(const short8*)&Wb[PW_P + o * CD + kk];
                accU[i] = __builtin_amdgcn_mfma_f32_16x16x32_bf16(wp, ft, accU[i], 0, 0, 0);
            }
        }

        f32x4 acc[2][2];
        // ---- pair (0,1): out_n = U/5 + x_n·M0
        #pragma unroll
        for (int n = 0; n < 2; ++n)
            #pragma unroll
            for (int i = 0; i < 2; ++i) acc[n][i] = (f32x4){0.f,0.f,0.f,0.f};
        #pragma unroll
        for (int m = 0; m < 4; ++m) {
            const int kk = m * 32 + hi * 8;
            short8 f0 = *(const short8*)&A[LIDX(0, lo, kk)];
            short8 f1 = *(const short8*)&A[LIDX(1, lo, kk)];
            #pragma unroll
            for (int i = 0; i < 2; ++i) {
                const int o = obase + i * 16 + lo;
                short8 wm = *(const short8*)&Wb[PW_M0 + o * CD + kk];
                acc[0][i] = __builtin_amdgcn_mfma_f32_16x16x32_bf16(wm, f0, acc[0][i], 0, 0, 0);
                acc[1][i] = __builtin_amdgcn_mfma_f32_16x16x32_bf16(wm, f1, acc[1][i], 0, 0, 0);
            }
        }
        #pragma unroll
        for (int n = 0; n < 2; ++n)
            #pragma unroll
            for (int i = 0; i < 2; ++i) acc[n][i] += 0.2f * accU[i];
        storePair(0, 1, acc, orow);           // ~2/3 phase to drain

        // ---- pair (2,5): out2 = U/4 + x2·M2 + x5·N ; out5 = U/4 + x5·M2 + x2·N
        #pragma unroll
        for (int n = 0; n < 2; ++n)
            #pragma unroll
            for (int i = 0; i < 2; ++i) acc[n][i] = (f32x4){0.f,0.f,0.f,0.f};
        #pragma unroll
        for (int m = 0; m < 4; ++m) {
            const int kk = m * 32 + hi * 8;
            short8 fa = *(const short8*)&A[LIDX(2, lo, kk)];
            short8 fb = *(const short8*)&A[LIDX(5, lo, kk)];
            #pragma unroll
            for (int i = 0; i < 2; ++i) {
                const int o = obase + i * 16 + lo;
                short8 wm = *(const short8*)&Wb[PW_M2 + o * CD + kk];
                short8 wn = *(const short8*)&Wb[PW_N  + o * CD + kk];
                acc[0][i] = __builtin_amdgcn_mfma_f32_16x16x32_bf16(wm, fa, acc[0][i], 0, 0, 0);
                acc[0][i] = __builtin_amdgcn_mfma_f32_16x16x32_bf16(wn, fb, acc[0][i], 0, 0, 0);
                acc[1][i] = __builtin_amdgcn_mfma_f32_16x16x32_bf16(wm, fb, acc[1][i], 0, 0, 0);
                acc[1][i] = __builtin_amdgcn_mfma_f32_16x16x32_bf16(wn, fa, acc[1][i], 0, 0, 0);
            }
        }
        #pragma unroll
        for (int n = 0; n < 2; ++n)
            #pragma unroll
            for (int i = 0; i < 2; ++i) acc[n][i] += 0.25f * accU[i];
        storePair(2, 5, acc, orow);           // ~1/3 phase to drain

        // ---- pair (3,4): held across barrier (R13's winning schedule)
        #pragma unroll
        for (int n = 0; n < 2; ++n)
            #pragma unroll
            for (int i = 0; i < 2; ++i) accH[n][i] = (f32x4){0.f,0.f,0.f,0.f};
        #pragma unroll
        for (int m = 0; m < 4; ++m) {
            const int kk = m * 32 + hi * 8;
            short8 fa = *(const short8*)&A[LIDX(3, lo, kk)];
            short8 fb = *(const short8*)&A[LIDX(4, lo, kk)];
            #pragma unroll
            for (int i = 0; i < 2; ++i) {
                const int o = obase + i * 16 + lo;
                short8 wm = *(const short8*)&Wb[PW_M2 + o * CD + kk];
                short8 wn = *(const short8*)&Wb[PW_N  + o * CD + kk];
                accH[0][i] = __builtin_amdgcn_mfma_f32_16x16x32_bf16(wm, fa, accH[0][i], 0, 0, 0);
                accH[0][i] = __builtin_amdgcn_mfma_f32_16x16x32_bf16(wn, fb, accH[0][i], 0, 0, 0);
                accH[1][i] = __builtin_amdgcn_mfma_f32_16x16x32_bf16(wm, fb, accH[1][i], 0, 0, 0);
                accH[1][i] = __builtin_amdgcn_mfma_f32_16x16x32_bf16(wn, fa, accH[1][i], 0, 0, 0);
            }
        }
        #pragma unroll
        for (int n = 0; n < 2; ++n)
            #pragma unroll
            for (int i = 0; i < 2; ++i) accH[n][i] += 0.25f * accU[i];
        prevRow = orow;

        __syncthreads();                      // barrier1: A reads done, DMA drained
        if (havenext) convert((it + 1) & 1);  // no stores in this window
        __syncthreads();                      // barrier2: publish A
    }
    storePair(3, 4, accH, prevRow);           // final held pair
}

extern "C" void kernel_launch(void* const* d_in, const int* in_sizes, int n_in,
                              void* d_out, int out_size, void* d_ws, size_t ws_size,
                              hipStream_t stream) {
    const float* x  = (const float*)d_in[0];
    const float* Wl = (const float*)d_in[1];
    const float* Wr = (const float*)d_in[2];
    const float* b  = (const float*)d_in[3];
    float* out = (float*)d_out;
    short* Wb = (short*)d_ws;   // 4 x 64 KB bf16 weight combos = 256 KB

    prep_w<<<dim3(16), dim3(256), 0, stream>>>(Wl, Wr, Wb);
    sage_v16<<<dim3(NBLK), dim3(512), 0, stream>>>(x, Wb, b, out);
}